// Round 1
// baseline (81.444 us; speedup 1.0000x reference)
//
#include <hip/hip_runtime.h>
#include <math.h>

#define NPATCH 196
#define NFEAT  784
#define NCLS   10

// Wire w (w=0 most significant) has bit stride 8>>w in the 16-state index.

template<int STRIDE>
__device__ __forceinline__ void ry_gate(float* sr, float* si, float c, float s) {
    #pragma unroll
    for (int g = 0; g < 8; ++g) {
        const int lo = g & (STRIDE - 1);
        const int s0 = ((g ^ lo) << 1) | lo;   // index with wire-bit = 0
        const int s1 = s0 | STRIDE;
        float r0 = sr[s0], r1 = sr[s1];
        float i0 = si[s0], i1 = si[s1];
        sr[s0] = c * r0 - s * r1;  sr[s1] = s * r0 + c * r1;
        si[s0] = c * i0 - s * i1;  si[s1] = s * i0 + c * i1;
    }
}

template<int STRIDE>
__device__ __forceinline__ void rz_gate(float* sr, float* si, float c, float s) {
    // bit=0: multiply by (c - i s); bit=1: multiply by (c + i s)
    #pragma unroll
    for (int idx = 0; idx < 16; ++idx) {
        float r = sr[idx], im = si[idx];
        if (idx & STRIDE) { sr[idx] = c * r - s * im; si[idx] = c * im + s * r; }
        else              { sr[idx] = c * r + s * im; si[idx] = c * im - s * r; }
    }
}

template<int SC, int ST>
__device__ __forceinline__ void cnot_gate(float* sr, float* si) {
    #pragma unroll
    for (int idx = 0; idx < 16; ++idx) {
        if ((idx & SC) && !(idx & ST)) {
            const int j = idx | ST;
            float tr = sr[idx]; sr[idx] = sr[j]; sr[j] = tr;
            float ti = si[idx]; si[idx] = si[j]; si[j] = ti;
        }
    }
}

__global__ __launch_bounds__(256)
void quanv_fused(const float* __restrict__ x, const float* __restrict__ vp,
                 const float* __restrict__ W, const float* __restrict__ bias,
                 float* __restrict__ out) {
    __shared__ float feats[NFEAT];
    __shared__ float redbuf[4][NCLS];
    __shared__ float logitsS[NCLS];

    const int b = blockIdx.x;
    const int t = threadIdx.x;

    if (t < NPATCH) {
        const int i = t / 14;
        const int j = t - i * 14;
        const float* xb = x + b * 784;
        const float* r0p = xb + (2 * i) * 28 + 2 * j;
        const float* r1p = r0p + 28;
        const float a0 = r0p[0], a1 = r0p[1], a2 = r1p[0], a3 = r1p[1];

        float ec[4], es[4];
        __sincosf(0.5f * a0, &es[0], &ec[0]);
        __sincosf(0.5f * a1, &es[1], &ec[1]);
        __sincosf(0.5f * a2, &es[2], &ec[2]);
        __sincosf(0.5f * a3, &es[3], &ec[3]);

        // Encoding: product state, purely real.
        float sr[16], si[16];
        #pragma unroll
        for (int s = 0; s < 16; ++s) {
            const float v = ((s & 8) ? es[0] : ec[0]) * ((s & 4) ? es[1] : ec[1])
                          * ((s & 2) ? es[2] : ec[2]) * ((s & 1) ? es[3] : ec[3]);
            sr[s] = v;
            si[s] = 0.0f;   // compiler folds zeros through the first RY layer
        }

        #pragma unroll
        for (int l = 0; l < 2; ++l) {
            const float* p = vp + l * 8;
            float gc, gs;
            __sincosf(0.5f * p[0], &gs, &gc); ry_gate<8>(sr, si, gc, gs);
            __sincosf(0.5f * p[1], &gs, &gc); ry_gate<4>(sr, si, gc, gs);
            __sincosf(0.5f * p[2], &gs, &gc); ry_gate<2>(sr, si, gc, gs);
            __sincosf(0.5f * p[3], &gs, &gc); ry_gate<1>(sr, si, gc, gs);
            __sincosf(0.5f * p[4], &gs, &gc); rz_gate<8>(sr, si, gc, gs);
            __sincosf(0.5f * p[5], &gs, &gc); rz_gate<4>(sr, si, gc, gs);
            __sincosf(0.5f * p[6], &gs, &gc); rz_gate<2>(sr, si, gc, gs);
            __sincosf(0.5f * p[7], &gs, &gc); rz_gate<1>(sr, si, gc, gs);
            cnot_gate<8, 4>(sr, si);
            cnot_gate<4, 2>(sr, si);
            cnot_gate<2, 1>(sr, si);
        }

        // Z expectations per wire.
        float e0 = 0.f, e1 = 0.f, e2 = 0.f, e3 = 0.f;
        #pragma unroll
        for (int s = 0; s < 16; ++s) {
            const float pr = sr[s] * sr[s] + si[s] * si[s];
            e0 += (s & 8) ? -pr : pr;
            e1 += (s & 4) ? -pr : pr;
            e2 += (s & 2) ? -pr : pr;
            e3 += (s & 1) ? -pr : pr;
        }
        feats[t * 4 + 0] = e0;
        feats[t * 4 + 1] = e1;
        feats[t * 4 + 2] = e2;
        feats[t * 4 + 3] = e3;
    }
    __syncthreads();

    // logits[c] = sum_k feats[k] * W[c,k]  (+ bias)
    float acc[NCLS];
    #pragma unroll
    for (int c = 0; c < NCLS; ++c) acc[c] = 0.0f;
    for (int k = t; k < NFEAT; k += 256) {
        const float f = feats[k];
        #pragma unroll
        for (int c = 0; c < NCLS; ++c) acc[c] += f * W[c * NFEAT + k];
    }
    #pragma unroll
    for (int off = 32; off > 0; off >>= 1) {
        #pragma unroll
        for (int c = 0; c < NCLS; ++c) acc[c] += __shfl_down(acc[c], off, 64);
    }
    const int wave = t >> 6, lane = t & 63;
    if (lane == 0) {
        #pragma unroll
        for (int c = 0; c < NCLS; ++c) redbuf[wave][c] = acc[c];
    }
    __syncthreads();
    if (t < NCLS) {
        logitsS[t] = redbuf[0][t] + redbuf[1][t] + redbuf[2][t] + redbuf[3][t] + bias[t];
    }
    __syncthreads();
    if (t < NCLS) {
        float m = -1e30f;
        #pragma unroll
        for (int c = 0; c < NCLS; ++c) m = fmaxf(m, logitsS[c]);
        float ssum = 0.0f;
        #pragma unroll
        for (int c = 0; c < NCLS; ++c) ssum += __expf(logitsS[c] - m);
        out[b * NCLS + t] = logitsS[t] - m - __logf(ssum);
    }
}

extern "C" void kernel_launch(void* const* d_in, const int* in_sizes, int n_in,
                              void* d_out, int out_size, void* d_ws, size_t ws_size,
                              hipStream_t stream) {
    const float* x  = (const float*)d_in[0];   // (2048, 28, 28)
    const float* vp = (const float*)d_in[1];   // (2, 2, 4)
    const float* W  = (const float*)d_in[2];   // (10, 784)
    const float* bb = (const float*)d_in[3];   // (10,)
    float* out = (float*)d_out;                // (2048, 10)

    quanv_fused<<<2048, 256, 0, stream>>>(x, vp, W, bb, out);
}

// Round 2
// 73.239 us; speedup vs baseline: 1.1120x; 1.1120x over previous
//
#include <hip/hip_runtime.h>
#include <math.h>

#define NPATCH 196
#define NCLS   10

// Wire w (w=0 most significant) has bit stride 8>>w in the 16-state index.

template<int STRIDE>
__device__ __forceinline__ void ry_real(float* sr, float c, float s) {
    #pragma unroll
    for (int g = 0; g < 8; ++g) {
        const int lo = g & (STRIDE - 1);
        const int s0 = ((g ^ lo) << 1) | lo;
        const int s1 = s0 | STRIDE;
        float r0 = sr[s0], r1 = sr[s1];
        sr[s0] = c * r0 - s * r1;
        sr[s1] = s * r0 + c * r1;
    }
}

template<int STRIDE>
__device__ __forceinline__ void ry_cplx(float* sr, float* si, float c, float s) {
    #pragma unroll
    for (int g = 0; g < 8; ++g) {
        const int lo = g & (STRIDE - 1);
        const int s0 = ((g ^ lo) << 1) | lo;
        const int s1 = s0 | STRIDE;
        float r0 = sr[s0], r1 = sr[s1];
        float i0 = si[s0], i1 = si[s1];
        sr[s0] = c * r0 - s * r1;  sr[s1] = s * r0 + c * r1;
        si[s0] = c * i0 - s * i1;  si[s1] = s * i0 + c * i1;
    }
}

template<int SC, int ST>
__device__ __forceinline__ void cnot_gate(float* sr, float* si) {
    #pragma unroll
    for (int idx = 0; idx < 16; ++idx) {
        if ((idx & SC) && !(idx & ST)) {
            const int j = idx | ST;
            float tr = sr[idx]; sr[idx] = sr[j]; sr[j] = tr;
            float ti = si[idx]; si[idx] = si[j]; si[j] = ti;
        }
    }
}

__global__ __launch_bounds__(256)
void quanv_fused(const float* __restrict__ x, const float* __restrict__ vp,
                 const float* __restrict__ W, const float* __restrict__ bias,
                 float* __restrict__ out) {
    // Uniform tables: RY (c,s) per layer/wire; fused-RZ diagonal phasors per layer/state.
    __shared__ float ry_t[2][4][2];     // [layer][wire][{c,s}]
    __shared__ float ph_t[2][16][2];    // [layer][state][{cos,sin}]
    __shared__ float redbuf[4][NCLS];
    __shared__ float logitsS[NCLS];

    const int b = blockIdx.x;
    const int t = threadIdx.x;

    // ---- uniform table build (idle-lane work; 40 threads, 1 sincos each) ----
    if (t < 40) {
        float vc, vs;
        if (t < 32) {
            const int l = t >> 4, k = t & 15;
            const float* rz = vp + l * 8 + 4;
            // RZ(theta): bit=0 -> e^{-i t/2}, bit=1 -> e^{+i t/2}. Wire w <-> bit (3-w).
            float phi = ((k >> 3) & 1) ? 0.5f * rz[0] : -0.5f * rz[0];
            phi      += ((k >> 2) & 1) ? 0.5f * rz[1] : -0.5f * rz[1];
            phi      += ((k >> 1) & 1) ? 0.5f * rz[2] : -0.5f * rz[2];
            phi      += ( k       & 1) ? 0.5f * rz[3] : -0.5f * rz[3];
            __sincosf(phi, &vs, &vc);
            ph_t[l][k][0] = vc; ph_t[l][k][1] = vs;
        } else {
            const int idx = t - 32, l = idx >> 2, w = idx & 3;
            float h = 0.5f * vp[l * 8 + w];
            __sincosf(h, &vs, &vc);
            ry_t[l][w][0] = vc; ry_t[l][w][1] = vs;
        }
    }
    __syncthreads();

    float acc[NCLS];
    #pragma unroll
    for (int c = 0; c < NCLS; ++c) acc[c] = 0.0f;

    if (t < NPATCH) {
        const int i = t / 14;
        const int j = t - i * 14;
        const float* xb = x + b * 784;
        const float* r0p = xb + (2 * i) * 28 + 2 * j;
        const float* r1p = r0p + 28;
        const float a0 = r0p[0], a1 = r0p[1], a2 = r1p[0], a3 = r1p[1];

        float ec[4], es[4];
        __sincosf(0.5f * a0, &es[0], &ec[0]);
        __sincosf(0.5f * a1, &es[1], &ec[1]);
        __sincosf(0.5f * a2, &es[2], &ec[2]);
        __sincosf(0.5f * a3, &es[3], &ec[3]);

        // Encoding: real product state via subproduct tree (24 muls).
        float p01[4], p23[4];
        p01[0] = ec[0] * ec[1]; p01[1] = ec[0] * es[1];
        p01[2] = es[0] * ec[1]; p01[3] = es[0] * es[1];
        p23[0] = ec[2] * ec[3]; p23[1] = ec[2] * es[3];
        p23[2] = es[2] * ec[3]; p23[3] = es[2] * es[3];
        float sr[16], si[16];
        #pragma unroll
        for (int s = 0; s < 16; ++s) sr[s] = p01[s >> 2] * p23[s & 3];

        // ---- layer 0: RY x4 on REAL state, fused diagonal, CNOT chain ----
        ry_real<8>(sr, ry_t[0][0][0], ry_t[0][0][1]);
        ry_real<4>(sr, ry_t[0][1][0], ry_t[0][1][1]);
        ry_real<2>(sr, ry_t[0][2][0], ry_t[0][2][1]);
        ry_real<1>(sr, ry_t[0][3][0], ry_t[0][3][1]);
        #pragma unroll
        for (int k = 0; k < 16; ++k) {   // real -> complex: amp *= (c + i s)
            float r = sr[k];
            sr[k] = r * ph_t[0][k][0];
            si[k] = r * ph_t[0][k][1];
        }
        cnot_gate<8, 4>(sr, si);
        cnot_gate<4, 2>(sr, si);
        cnot_gate<2, 1>(sr, si);

        // ---- layer 1: RY x4 complex, fused diagonal, CNOT chain ----
        ry_cplx<8>(sr, si, ry_t[1][0][0], ry_t[1][0][1]);
        ry_cplx<4>(sr, si, ry_t[1][1][0], ry_t[1][1][1]);
        ry_cplx<2>(sr, si, ry_t[1][2][0], ry_t[1][2][1]);
        ry_cplx<1>(sr, si, ry_t[1][3][0], ry_t[1][3][1]);
        #pragma unroll
        for (int k = 0; k < 16; ++k) {
            float c = ph_t[1][k][0], s = ph_t[1][k][1];
            float r = sr[k], im = si[k];
            sr[k] = r * c - im * s;
            si[k] = im * c + r * s;
        }
        cnot_gate<8, 4>(sr, si);
        cnot_gate<4, 2>(sr, si);
        cnot_gate<2, 1>(sr, si);

        // ---- Z expectations via sum/diff tree ----
        float p[16];
        #pragma unroll
        for (int k = 0; k < 16; ++k) p[k] = sr[k] * sr[k] + si[k] * si[k];
        float q[8], e3 = 0.f;
        #pragma unroll
        for (int k = 0; k < 8; ++k) { e3 += p[2*k] - p[2*k+1]; q[k] = p[2*k] + p[2*k+1]; }
        float r4[4], e2 = 0.f;
        #pragma unroll
        for (int k = 0; k < 4; ++k) { e2 += q[2*k] - q[2*k+1]; r4[k] = q[2*k] + q[2*k+1]; }
        const float e1 = (r4[0] - r4[1]) + (r4[2] - r4[3]);
        const float e0 = (r4[0] + r4[1]) - (r4[2] + r4[3]);

        // ---- GEMV contribution direct from registers: coalesced float4 W loads ----
        const float4* __restrict__ W4 = (const float4*)W;
        #pragma unroll
        for (int c = 0; c < NCLS; ++c) {
            const float4 w = W4[c * 196 + t];
            acc[c] = e0 * w.x + e1 * w.y + e2 * w.z + e3 * w.w;
        }
    }

    // ---- block reduction of 10 logits ----
    #pragma unroll
    for (int off = 32; off > 0; off >>= 1) {
        #pragma unroll
        for (int c = 0; c < NCLS; ++c) acc[c] += __shfl_down(acc[c], off, 64);
    }
    const int wave = t >> 6, lane = t & 63;
    if (lane == 0) {
        #pragma unroll
        for (int c = 0; c < NCLS; ++c) redbuf[wave][c] = acc[c];
    }
    __syncthreads();
    if (t < NCLS) {
        logitsS[t] = redbuf[0][t] + redbuf[1][t] + redbuf[2][t] + redbuf[3][t] + bias[t];
    }
    __syncthreads();
    if (t < NCLS) {
        float m = -1e30f;
        #pragma unroll
        for (int c = 0; c < NCLS; ++c) m = fmaxf(m, logitsS[c]);
        float ssum = 0.0f;
        #pragma unroll
        for (int c = 0; c < NCLS; ++c) ssum += __expf(logitsS[c] - m);
        out[b * NCLS + t] = logitsS[t] - m - __logf(ssum);
    }
}

extern "C" void kernel_launch(void* const* d_in, const int* in_sizes, int n_in,
                              void* d_out, int out_size, void* d_ws, size_t ws_size,
                              hipStream_t stream) {
    const float* x  = (const float*)d_in[0];   // (2048, 28, 28)
    const float* vp = (const float*)d_in[1];   // (2, 2, 4)
    const float* W  = (const float*)d_in[2];   // (10, 784)
    const float* bb = (const float*)d_in[3];   // (10,)
    float* out = (float*)d_out;                // (2048, 10)

    quanv_fused<<<2048, 256, 0, stream>>>(x, vp, W, bb, out);
}

// Round 3
// 71.195 us; speedup vs baseline: 1.1440x; 1.0287x over previous
//
#include <hip/hip_runtime.h>
#include <math.h>

#define NCLS 10

// Wire w (w=0..3) has bit stride 8>>w in the 16-state index (wire0 <-> bit3).

template<int STRIDE>
__device__ __forceinline__ void ry_cplx(float* sr, float* si, float c, float s) {
    #pragma unroll
    for (int g = 0; g < 8; ++g) {
        const int lo = g & (STRIDE - 1);
        const int s0 = ((g ^ lo) << 1) | lo;
        const int s1 = s0 | STRIDE;
        float r0 = sr[s0], r1 = sr[s1];
        float i0 = si[s0], i1 = si[s1];
        sr[s0] = c * r0 - s * r1;  sr[s1] = s * r0 + c * r1;
        si[s0] = c * i0 - s * i1;  si[s1] = s * i0 + c * i1;
    }
}

template<int SC, int ST>
__device__ __forceinline__ void cnot_gate(float* sr, float* si) {
    #pragma unroll
    for (int idx = 0; idx < 16; ++idx) {
        if ((idx & SC) && !(idx & ST)) {
            const int j = idx | ST;
            float tr = sr[idx]; sr[idx] = sr[j]; sr[j] = tr;
            float ti = si[idx]; si[idx] = si[j]; si[j] = ti;
        }
    }
}

__global__ __launch_bounds__(256)
void quanv_fused(const float* __restrict__ x, const float* __restrict__ vp,
                 const float* __restrict__ W, const float* __restrict__ bias,
                 float* __restrict__ out) {
    // Layer-0 fused-RZ diagonal phasors (16) + layer-1 RY (c,s) per wire (4).
    __shared__ float ph_c[16], ph_s[16];
    __shared__ float ry1c[4], ry1s[4];
    __shared__ float4 feats4[196];          // one float4 (e0..e3) per patch
    __shared__ float logitsS[NCLS];

    const int b = blockIdx.x;
    const int t = threadIdx.x;

    // ---- uniform tables on idle wave-3 lanes (overlaps sim prologue) ----
    if (t >= 224 && t < 244) {
        const int u = t - 224;
        float vc, vs;
        if (u < 16) {
            const float* rz = vp + 4;       // layer-0 RZ params
            // phase: bit set -> +theta/2, clear -> -theta/2 (verified sign conv.)
            float phi = ((u & 8) ? 0.5f : -0.5f) * rz[0]
                      + ((u & 4) ? 0.5f : -0.5f) * rz[1]
                      + ((u & 2) ? 0.5f : -0.5f) * rz[2]
                      + ((u & 1) ? 0.5f : -0.5f) * rz[3];
            __sincosf(phi, &vs, &vc);
            ph_c[u] = vc; ph_s[u] = vs;
        } else {
            const int w = u - 16;           // layer-1 RY
            __sincosf(0.5f * vp[8 + w], &vs, &vc);
            ry1c[w] = vc; ry1s[w] = vs;
        }
    }

    const bool is_sim = (t < 196);
    float sr[16];
    if (is_sim) {
        const int i = t / 14;
        const int j = t - i * 14;
        const float* xb = x + b * 784 + 2 * i * 28 + 2 * j;
        const float2 A  = *(const float2*)xb;          // pixels 0,1
        const float2 Bv = *(const float2*)(xb + 28);   // pixels 2,3

        // Encoding RY(a_w) composed with layer-0 RY(vp_w): RY(a_w + vp_w).
        float ec[4], es[4];
        __sincosf(0.5f * (A.x  + vp[0]), &es[0], &ec[0]);
        __sincosf(0.5f * (A.y  + vp[1]), &es[1], &ec[1]);
        __sincosf(0.5f * (Bv.x + vp[2]), &es[2], &ec[2]);
        __sincosf(0.5f * (Bv.y + vp[3]), &es[3], &ec[3]);

        // Real product state via subproduct tree.
        float p01[4], p23[4];
        p01[0] = ec[0] * ec[1]; p01[1] = ec[0] * es[1];
        p01[2] = es[0] * ec[1]; p01[3] = es[0] * es[1];
        p23[0] = ec[2] * ec[3]; p23[1] = ec[2] * es[3];
        p23[2] = es[2] * ec[3]; p23[3] = es[2] * es[3];
        #pragma unroll
        for (int s = 0; s < 16; ++s) sr[s] = p01[s >> 2] * p23[s & 3];
    }
    __syncthreads();   // publish tables

    if (is_sim) {
        float si_[16];
        // Layer-0 fused RZ diagonal: real -> complex (amp *= c + i s).
        #pragma unroll
        for (int k = 0; k < 16; ++k) {
            float r = sr[k];
            sr[k]  = r * ph_c[k];
            si_[k] = r * ph_s[k];
        }
        cnot_gate<8, 4>(sr, si_);
        cnot_gate<4, 2>(sr, si_);
        cnot_gate<2, 1>(sr, si_);

        // Layer-1 RY (complex). Layer-1 RZ is diagonal-unitary and layer-1
        // CNOTs are basis permutations -> both invisible to |amp|^2; the CNOT
        // permutation is folded into the measurement sign masks below.
        ry_cplx<8>(sr, si_, ry1c[0], ry1s[0]);
        ry_cplx<4>(sr, si_, ry1c[1], ry1s[1]);
        ry_cplx<2>(sr, si_, ry1c[2], ry1s[2]);
        ry_cplx<1>(sr, si_, ry1c[3], ry1s[3]);

        float p[16];
        #pragma unroll
        for (int k = 0; k < 16; ++k) p[k] = sr[k] * sr[k] + si_[k] * si_[k];

        // Post-CNOT-chain signs: e0<-b3, e1<-b3^b2, e2<-b3^b2^b1, e3<-parity.
        float s8[8], d8[8];
        #pragma unroll
        for (int k = 0; k < 8; ++k) { s8[k] = p[2*k] + p[2*k+1]; d8[k] = p[2*k] - p[2*k+1]; }
        const float e3 =  d8[0] - d8[1] - d8[2] + d8[3] - d8[4] + d8[5] + d8[6] - d8[7];
        const float e2 =  s8[0] - s8[1] - s8[2] + s8[3] - s8[4] + s8[5] + s8[6] - s8[7];
        float S0 = s8[0] + s8[1], S1 = s8[2] + s8[3], S2 = s8[4] + s8[5], S3 = s8[6] + s8[7];
        const float e1 = S0 - S1 - S2 + S3;
        const float e0 = S0 + S1 - S2 - S3;

        feats4[t] = make_float4(e0, e1, e2, e3);
    }
    __syncthreads();

    // ---- GEMV: thread (c = t>>4 in [0,10), j = t&15), strided float4 k-chunks ----
    const int c = t >> 4, j = t & 15;
    float acc = 0.0f;
    if (c < NCLS) {
        const float4* __restrict__ W4 = (const float4*)W;   // row c at float4 idx c*196
        #pragma unroll
        for (int i2 = 0; i2 < 12; ++i2) {
            const int v = j + 16 * i2;
            const float4 f = feats4[v];
            const float4 w = W4[c * 196 + v];
            acc += f.x * w.x + f.y * w.y + f.z * w.z + f.w * w.w;
        }
        if (j < 4) {            // tail: float4 indices 192..195
            const int v = j + 192;
            const float4 f = feats4[v];
            const float4 w = W4[c * 196 + v];
            acc += f.x * w.x + f.y * w.y + f.z * w.z + f.w * w.w;
        }
    }
    // reduce across the 16-lane subgroup
    acc += __shfl_down(acc, 8, 16);
    acc += __shfl_down(acc, 4, 16);
    acc += __shfl_down(acc, 2, 16);
    acc += __shfl_down(acc, 1, 16);
    if (j == 0 && c < NCLS) logitsS[c] = acc + bias[c];
    __syncthreads();

    if (t < NCLS) {
        float m = -1e30f;
        #pragma unroll
        for (int k = 0; k < NCLS; ++k) m = fmaxf(m, logitsS[k]);
        float ssum = 0.0f;
        #pragma unroll
        for (int k = 0; k < NCLS; ++k) ssum += __expf(logitsS[k] - m);
        out[b * NCLS + t] = logitsS[t] - m - __logf(ssum);
    }
}

extern "C" void kernel_launch(void* const* d_in, const int* in_sizes, int n_in,
                              void* d_out, int out_size, void* d_ws, size_t ws_size,
                              hipStream_t stream) {
    const float* x  = (const float*)d_in[0];   // (2048, 28, 28)
    const float* vp = (const float*)d_in[1];   // (2, 2, 4)
    const float* W  = (const float*)d_in[2];   // (10, 784)
    const float* bb = (const float*)d_in[3];   // (10,)
    float* out = (float*)d_out;                // (2048, 10)

    quanv_fused<<<2048, 256, 0, stream>>>(x, vp, W, bb, out);
}

// Round 4
// 71.008 us; speedup vs baseline: 1.1470x; 1.0026x over previous
//
#include <hip/hip_runtime.h>
#include <math.h>

#define NCLS 10

// Wire w (w=0..3) has bit stride 8>>w in the 16-state index (wire0 <-> bit3).
// Complex amplitude = float2 (.x = re, .y = im); float2 elementwise math maps
// to v_pk_fma_f32 / v_pk_mul_f32 on gfx950 (packed FP32, full rate).

template<int STRIDE>
__device__ __forceinline__ void ry_cplx2(float2* a, float c, float s) {
    #pragma unroll
    for (int g = 0; g < 8; ++g) {
        const int lo = g & (STRIDE - 1);
        const int s0 = ((g ^ lo) << 1) | lo;
        const int s1 = s0 | STRIDE;
        const float2 a0 = a[s0], a1 = a[s1];
        a[s0] = make_float2(c * a0.x - s * a1.x, c * a0.y - s * a1.y);
        a[s1] = make_float2(s * a0.x + c * a1.x, s * a0.y + c * a1.y);
    }
}

template<int SC, int ST>
__device__ __forceinline__ void cnot2(float2* a) {
    #pragma unroll
    for (int idx = 0; idx < 16; ++idx) {
        if ((idx & SC) && !(idx & ST)) {
            const int j = idx | ST;
            const float2 tmp = a[idx]; a[idx] = a[j]; a[j] = tmp;
        }
    }
}

__global__ __launch_bounds__(256)
void quanv_fused(const float* __restrict__ x, const float* __restrict__ vp,
                 const float* __restrict__ W, const float* __restrict__ bias,
                 float* __restrict__ out) {
    __shared__ float2 ph2[16];          // layer-0 fused-RZ phasor (cos,sin)
    __shared__ float ry1c[4], ry1s[4];  // layer-1 RY
    __shared__ float4 feats4[196];
    __shared__ float logitsS[NCLS];

    const int b = blockIdx.x;
    const int t = threadIdx.x;

    // ---- uniform tables on idle wave-3 lanes (overlaps sim prologue) ----
    if (t >= 224 && t < 244) {
        const int u = t - 224;
        float vc, vs;
        if (u < 16) {
            const float* rz = vp + 4;   // layer-0 RZ params
            float phi = ((u & 8) ? 0.5f : -0.5f) * rz[0]
                      + ((u & 4) ? 0.5f : -0.5f) * rz[1]
                      + ((u & 2) ? 0.5f : -0.5f) * rz[2]
                      + ((u & 1) ? 0.5f : -0.5f) * rz[3];
            __sincosf(phi, &vs, &vc);
            ph2[u] = make_float2(vc, vs);
        } else {
            const int w = u - 16;       // layer-1 RY
            __sincosf(0.5f * vp[8 + w], &vs, &vc);
            ry1c[w] = vc; ry1s[w] = vs;
        }
    }

    const bool is_sim = (t < 196);
    float sr[16];
    if (is_sim) {
        const int i = t / 14;
        const int j = t - i * 14;
        const float* xb = x + b * 784 + 2 * i * 28 + 2 * j;
        const float2 A  = *(const float2*)xb;
        const float2 Bv = *(const float2*)(xb + 28);

        // Encoding RY(a_w) composed with layer-0 RY(vp_w): RY(a_w + vp_w).
        float ec[4], es[4];
        __sincosf(0.5f * (A.x  + vp[0]), &es[0], &ec[0]);
        __sincosf(0.5f * (A.y  + vp[1]), &es[1], &ec[1]);
        __sincosf(0.5f * (Bv.x + vp[2]), &es[2], &ec[2]);
        __sincosf(0.5f * (Bv.y + vp[3]), &es[3], &ec[3]);

        float p01[4], p23[4];
        p01[0] = ec[0] * ec[1]; p01[1] = ec[0] * es[1];
        p01[2] = es[0] * ec[1]; p01[3] = es[0] * es[1];
        p23[0] = ec[2] * ec[3]; p23[1] = ec[2] * es[3];
        p23[2] = es[2] * ec[3]; p23[3] = es[2] * es[3];
        #pragma unroll
        for (int s = 0; s < 16; ++s) sr[s] = p01[s >> 2] * p23[s & 3];
    }
    __syncthreads();   // publish tables

    if (is_sim) {
        float2 a[16];
        // Layer-0 fused RZ diagonal: real -> complex, one pk_mul per state.
        #pragma unroll
        for (int k = 0; k < 16; ++k) {
            const float2 ph = ph2[k];
            a[k] = make_float2(sr[k] * ph.x, sr[k] * ph.y);
        }
        cnot2<8, 4>(a);
        cnot2<4, 2>(a);
        cnot2<2, 1>(a);

        // Layer-1 RY (complex, packed). Layer-1 RZ + CNOTs are invisible to
        // |amp|^2; CNOT permutation folded into measurement sign masks below.
        ry_cplx2<8>(a, ry1c[0], ry1s[0]);
        ry_cplx2<4>(a, ry1c[1], ry1s[1]);
        ry_cplx2<2>(a, ry1c[2], ry1s[2]);
        ry_cplx2<1>(a, ry1c[3], ry1s[3]);

        float p[16];
        #pragma unroll
        for (int k = 0; k < 16; ++k) p[k] = a[k].x * a[k].x + a[k].y * a[k].y;

        // Post-CNOT-chain signs: e0<-b3, e1<-b3^b2, e2<-b3^b2^b1, e3<-parity.
        float s8[8], d8[8];
        #pragma unroll
        for (int k = 0; k < 8; ++k) { s8[k] = p[2*k] + p[2*k+1]; d8[k] = p[2*k] - p[2*k+1]; }
        const float e3 =  d8[0] - d8[1] - d8[2] + d8[3] - d8[4] + d8[5] + d8[6] - d8[7];
        const float e2 =  s8[0] - s8[1] - s8[2] + s8[3] - s8[4] + s8[5] + s8[6] - s8[7];
        const float S0 = s8[0] + s8[1], S1 = s8[2] + s8[3], S2 = s8[4] + s8[5], S3 = s8[6] + s8[7];
        const float e1 = S0 - S1 - S2 + S3;
        const float e0 = S0 + S1 - S2 - S3;

        feats4[t] = make_float4(e0, e1, e2, e3);
    }
    __syncthreads();

    // ---- GEMV: thread (c = t>>4 in [0,10), j = t&15), strided float4 chunks ----
    const int c = t >> 4, j = t & 15;
    float acc = 0.0f;
    if (c < NCLS) {
        const float4* __restrict__ W4 = (const float4*)W;
        #pragma unroll
        for (int i2 = 0; i2 < 12; ++i2) {
            const int v = j + 16 * i2;
            const float4 f = feats4[v];
            const float4 w = W4[c * 196 + v];
            acc += f.x * w.x + f.y * w.y + f.z * w.z + f.w * w.w;
        }
        if (j < 4) {
            const int v = j + 192;
            const float4 f = feats4[v];
            const float4 w = W4[c * 196 + v];
            acc += f.x * w.x + f.y * w.y + f.z * w.z + f.w * w.w;
        }
    }
    acc += __shfl_down(acc, 8, 16);
    acc += __shfl_down(acc, 4, 16);
    acc += __shfl_down(acc, 2, 16);
    acc += __shfl_down(acc, 1, 16);
    if (j == 0 && c < NCLS) logitsS[c] = acc + bias[c];
    __syncthreads();

    if (t < NCLS) {
        float m = -1e30f;
        #pragma unroll
        for (int k = 0; k < NCLS; ++k) m = fmaxf(m, logitsS[k]);
        float ssum = 0.0f;
        #pragma unroll
        for (int k = 0; k < NCLS; ++k) ssum += __expf(logitsS[k] - m);
        out[b * NCLS + t] = logitsS[t] - m - __logf(ssum);
    }
}

extern "C" void kernel_launch(void* const* d_in, const int* in_sizes, int n_in,
                              void* d_out, int out_size, void* d_ws, size_t ws_size,
                              hipStream_t stream) {
    const float* x  = (const float*)d_in[0];   // (2048, 28, 28)
    const float* vp = (const float*)d_in[1];   // (2, 2, 4)
    const float* W  = (const float*)d_in[2];   // (10, 784)
    const float* bb = (const float*)d_in[3];   // (10,)
    float* out = (float*)d_out;                // (2048, 10)

    quanv_fused<<<2048, 256, 0, stream>>>(x, vp, W, bb, out);
}